// Round 12
// baseline (229.151 us; speedup 1.0000x reference)
//
#include <hip/hip_runtime.h>
#include <math.h>

// ---------------------------------------------------------------------------
// GCN, atomic-free aggregation via per-call CSR (bucket by dst):
//   deg count (dst-partitioned) -> block scan(+dinv) -> add_offsets (fused
//   bsum scan) -> fill (dst-partitioned, XCD-local, u16)          [once]
//   gemm1 (MFMA 16x16x32 bf16, W frags in VGPRs): G1 = (x@W1)*dinv,
//     stored as TWO column planes Glo[M][32], Ghi[M][32] (3.2MB each).
//   aggmm<64>: 2-pass gather (pass p reads only plane p -> 3.2MB working set
//     fits the 4MiB per-XCD L2; a 128B line in a plane = 2 rows, so the LINE
//     footprint is genuinely halved — unlike column-splitting reads of an
//     unsplit [M][64] array where every row IS a full line). relu epilogue
//     into LDS Ys[16][72], then MFMA with W2 -> G2 planes.
//   aggmm<40>: same, MFMA with W3 -> G3[M][40] (unsplit; 4MB, borderline L2).
//   agg40_lsm: 40-wide gather + relu + log_softmax -> out.
// Gather shape (per pass): lane=(grp<<3)|sub, uint2 (4 bf16 = 8B), 8 lanes
// cover a 64B half-row, 8 edge rows/instr (512B); butterfly shfl_xor(8|16|32)
// on 4 accs = 12 DS/node/pass (24 total — same as the old 1-pass design).
// History: r7 4x4 reg-tile GEMM = occupancy crater; r9 LDS gemv = LDS-pipe
// bound; r10 MFMA-reg GEMM fixed it; r11 agg+GEMM fusion = -2us (aggs are
// gather-bound, not HBM-bound) -> this round attacks gather cache residency.
// cidx u16 (N_NODES=50000<65536).
// NOTE: no hipMemsetAsync — rocclr fillBuffer took 45.9us for 195KB in-graph.
// ---------------------------------------------------------------------------

#define DF 64
#define TB 256
#define NPART 8

typedef __attribute__((ext_vector_type(8))) short bf16x8;
typedef __attribute__((ext_vector_type(4))) float f32x4;

__device__ __forceinline__ unsigned short f2bf(float f) {
    union { float f; unsigned u; } c; c.f = f;
    unsigned u = c.u;
    return (unsigned short)((u + 0x7fffu + ((u >> 16) & 1u)) >> 16);   // RNE
}
__device__ __forceinline__ float bf2f(unsigned short h) {
    union { unsigned u; float f; } c; c.u = ((unsigned)h) << 16;
    return c.f;
}
__device__ __forceinline__ void acc_bf16x4(uint2 v, float* a) {
    a[0] += bf2f((unsigned short)(v.x & 0xffffu));
    a[1] += bf2f((unsigned short)(v.x >> 16));
    a[2] += bf2f((unsigned short)(v.y & 0xffffu));
    a[3] += bf2f((unsigned short)(v.y >> 16));
}

__global__ void zero_int_kernel(int* __restrict__ p, int n) {
    int i = blockIdx.x * blockDim.x + threadIdx.x;
    if (i < n) p[i] = 0;
}

__global__ void count_deg_part_kernel(const int* __restrict__ dst, int* __restrict__ deg,
                                      int e, int psize) {
    const int p   = blockIdx.x & (NPART - 1);
    const int sl  = blockIdx.x / NPART;
    const int nsl = gridDim.x / NPART;
    const int lo = p * psize, hi = lo + psize;
    for (int i = sl * TB + threadIdx.x; i < e; i += nsl * TB) {
        int d = dst[i];
        if (d >= lo && d < hi) atomicAdd(&deg[d], 1);
    }
}

// per-block exclusive scan of deg -> ex (partial), block totals -> bsum; also dinv
__global__ void scan_block_kernel(const int* __restrict__ deg, int* __restrict__ ex,
                                  int* __restrict__ bsum, float* __restrict__ dinv, int n) {
    __shared__ int s[TB];
    const int t = threadIdx.x;
    const int i = blockIdx.x * TB + t;
    int v = (i < n) ? deg[i] : 0;
    if (i < n) dinv[i] = rsqrtf((float)(v + 1));   // +1 self-loop
    s[t] = v; __syncthreads();
#pragma unroll
    for (int o = 1; o < TB; o <<= 1) {
        int u = (t >= o) ? s[t - o] : 0;
        __syncthreads();
        s[t] += u;
        __syncthreads();
    }
    if (i < n) ex[i] = s[t] - v;
    if (t == TB - 1) bsum[blockIdx.x] = s[TB - 1];
}

// each block redundantly scans bsum (nb <= 256) in LDS, then offsets its slice
__global__ void add_offsets_kernel(int* __restrict__ ex, const int* __restrict__ bsum,
                                   int* __restrict__ cursor, int n, int nb) {
    __shared__ int s[TB];
    const int t = threadIdx.x;
    int v = (t < nb) ? bsum[t] : 0;
    s[t] = v; __syncthreads();
#pragma unroll
    for (int o = 1; o < TB; o <<= 1) {
        int u = (t >= o) ? s[t - o] : 0;
        __syncthreads();
        s[t] += u;
        __syncthreads();
    }
    const int boff = (blockIdx.x > 0) ? s[blockIdx.x - 1] : 0;
    const int i = blockIdx.x * TB + t;
    if (i < n) {
        int r = ex[i] + boff;
        ex[i] = r;
        cursor[i] = r;
    }
}

__global__ void fill_csr_part_kernel(const int* __restrict__ src, const int* __restrict__ dst,
                                     int* __restrict__ cursor,
                                     unsigned short* __restrict__ cidx, int e, int psize) {
    const int p   = blockIdx.x & (NPART - 1);
    const int sl  = blockIdx.x / NPART;
    const int nsl = gridDim.x / NPART;
    const int lo = p * psize, hi = lo + psize;
    for (int i = sl * TB + threadIdx.x; i < e; i += nsl * TB) {
        int d = dst[i];
        if (d >= lo && d < hi) {
            int pos = atomicAdd(&cursor[d], 1);
            cidx[pos] = (unsigned short)src[i];
        }
    }
}

// G planes (bf16) = (X[M x 64] @ W1[64 x 64]) * dinv[row], via MFMA. Layer 1.
// Output column-split: Glo[M][32] (cols 0-31), Ghi[M][32] (cols 32-63).
__global__ __launch_bounds__(256) void gemm_mfma_kernel(
        const float* __restrict__ X, const float* __restrict__ W,
        const float* __restrict__ dinv,
        unsigned short* __restrict__ Glo, unsigned short* __restrict__ Ghi, int M) {
    const int lane = threadIdx.x & 63;
    const int wid  = threadIdx.x >> 6;         // 0..3
    const int t    = blockIdx.x * 4 + wid;     // row-tile index
    const int nt   = (M + 15) >> 4;
    if (t >= nt) return;
    const int n = lane & 15;
    const int g = lane >> 4;

    bf16x8 bf[4][2];
#pragma unroll
    for (int ct = 0; ct < 4; ++ct) {
        const int c = ct * 16 + n;
#pragma unroll
        for (int ks = 0; ks < 2; ++ks)
#pragma unroll
            for (int j = 0; j < 8; ++j)
                bf[ct][ks][j] = (short)f2bf(W[(ks * 32 + g * 8 + j) * 64 + c]);
    }

    const int row_a = t * 16 + n;
    const int ra = (row_a < M) ? row_a : (M - 1);
    bf16x8 af[2];
#pragma unroll
    for (int ks = 0; ks < 2; ++ks) {
        float4 p0 = *(const float4*)(X + (size_t)ra * 64 + ks * 32 + g * 8);
        float4 p1 = *(const float4*)(X + (size_t)ra * 64 + ks * 32 + g * 8 + 4);
        af[ks][0] = (short)f2bf(p0.x); af[ks][1] = (short)f2bf(p0.y);
        af[ks][2] = (short)f2bf(p0.z); af[ks][3] = (short)f2bf(p0.w);
        af[ks][4] = (short)f2bf(p1.x); af[ks][5] = (short)f2bf(p1.y);
        af[ks][6] = (short)f2bf(p1.z); af[ks][7] = (short)f2bf(p1.w);
    }

    const int rbase = t * 16 + g * 4;
    float di[4];
#pragma unroll
    for (int r = 0; r < 4; ++r) {
        int rr = rbase + r;
        di[r] = dinv[(rr < M) ? rr : (M - 1)];
    }

#pragma unroll
    for (int ct = 0; ct < 4; ++ct) {
        f32x4 acc = {0.f, 0.f, 0.f, 0.f};
        acc = __builtin_amdgcn_mfma_f32_16x16x32_bf16(af[0], bf[ct][0], acc, 0, 0, 0);
        acc = __builtin_amdgcn_mfma_f32_16x16x32_bf16(af[1], bf[ct][1], acc, 0, 0, 0);
        unsigned short* plane = (ct < 2) ? Glo : Ghi;
        const int c32 = (ct & 1) * 16 + n;
#pragma unroll
        for (int r = 0; r < 4; ++r) {
            const int row = rbase + r;
            if (row < M)
                plane[(size_t)row * 32 + c32] = f2bf(acc[r] * di[r]);
        }
    }
}

// Fused: aggregate 16 nodes (4 per wave, 2 passes over column planes) +
// next-layer MFMA GEMM. NCO=64 -> split output planes; NCO=40 -> plain [M][40].
template <int NCO>
__global__ __launch_bounds__(256) void aggmm_kernel(
        const unsigned short* __restrict__ Glo, const unsigned short* __restrict__ Ghi,
        const int* __restrict__ rowptr, const int* __restrict__ deg,
        const unsigned short* __restrict__ cidx,
        const float* __restrict__ dinv, const float* __restrict__ b,
        const float* __restrict__ Wn,
        unsigned short* __restrict__ Olo, unsigned short* __restrict__ Ohi, int M) {
    __shared__ unsigned short Ys[16][72];      // +8 pad: stride 144B
    __shared__ float ds[16];
    const int tid  = threadIdx.x;
    const int lane = tid & 63;
    const int wid  = tid >> 6;                 // 0..3
    const int base = blockIdx.x * 16;
    const int grp8 = lane >> 3;                // 0..7 edge slot
    const int sub8 = lane & 7;                 // 0..7 col quad (4 bf16 = 8B)
    const int n16 = lane & 15;
    const int g16 = lane >> 4;

    // B fragments for this wave's col-tile ct = wid
    const bool wactive = (wid * 16 < NCO);
    bf16x8 bf[2];
    if (wactive) {
        const int c = wid * 16 + n16;
#pragma unroll
        for (int ks = 0; ks < 2; ++ks)
#pragma unroll
            for (int j = 0; j < 8; ++j) {
                const int k = ks * 32 + g16 * 8 + j;
                float w = (c < NCO) ? Wn[k * NCO + c] : 0.f;
                bf[ks][j] = (short)f2bf(w);
            }
    }

    // agg phase: 2 passes (plane half), wave wid owns rows wid*4 .. wid*4+3
#pragma unroll
    for (int half = 0; half < 2; ++half) {
        const unsigned short* Gh = half ? Ghi : Glo;
        for (int i = 0; i < 4; ++i) {
            const int nrow  = wid * 4 + i;
            const int node0 = base + nrow;
            const int node  = (node0 < M) ? node0 : (M - 1);   // clamped: garbage ok
            const int start = rowptr[node];
            const int cnt   = deg[node];

            float a[4] = {0.f, 0.f, 0.f, 0.f};
            float c4[4] = {0.f, 0.f, 0.f, 0.f};
            for (int bs = 0; bs < cnt; bs += 64) {
                const int nthis = min(64, cnt - bs);
                int myidx = (lane < nthis) ? (int)cidx[start + bs + lane] : 0;
                int j = 0;
                for (; j + 16 <= nthis; j += 16) {
                    int s0 = __shfl(myidx, j + grp8, 64);
                    int s1 = __shfl(myidx, j + 8 + grp8, 64);
                    uint2 v0 = *(const uint2*)(Gh + (size_t)s0 * 32 + sub8 * 4);
                    uint2 v1 = *(const uint2*)(Gh + (size_t)s1 * 32 + sub8 * 4);
                    acc_bf16x4(v0, a);
                    acc_bf16x4(v1, c4);
                }
                if (j + 8 <= nthis) {
                    int s0 = __shfl(myidx, j + grp8, 64);
                    uint2 v0 = *(const uint2*)(Gh + (size_t)s0 * 32 + sub8 * 4);
                    acc_bf16x4(v0, a);
                    j += 8;
                }
                const int rem = nthis - j;
                if (grp8 < rem) {
                    int s0 = __shfl(myidx, j + grp8, 64);
                    uint2 v0 = *(const uint2*)(Gh + (size_t)s0 * 32 + sub8 * 4);
                    acc_bf16x4(v0, c4);
                }
            }
#pragma unroll
            for (int k = 0; k < 4; ++k) a[k] += c4[k];
#pragma unroll
            for (int k = 0; k < 4; ++k) {
                a[k] += __shfl_xor(a[k], 8, 64);
                a[k] += __shfl_xor(a[k], 16, 64);
                a[k] += __shfl_xor(a[k], 32, 64);
            }
            if (grp8 == 0) {
                // self + bias + relu for cols half*32 + sub8*4 .. +4
                uint2 sv = *(const uint2*)(Gh + (size_t)node * 32 + sub8 * 4);
                float4 bb = *(const float4*)(b + half * 32 + sub8 * 4);
                const float di = dinv[node];
                float v0 = fmaxf((a[0] + bf2f((unsigned short)(sv.x & 0xffffu))) * di + bb.x, 0.f);
                float v1 = fmaxf((a[1] + bf2f((unsigned short)(sv.x >> 16)))     * di + bb.y, 0.f);
                float v2 = fmaxf((a[2] + bf2f((unsigned short)(sv.y & 0xffffu))) * di + bb.z, 0.f);
                float v3 = fmaxf((a[3] + bf2f((unsigned short)(sv.y >> 16)))     * di + bb.w, 0.f);
                uint2 o;
                o.x = (unsigned)f2bf(v0) | ((unsigned)f2bf(v1) << 16);
                o.y = (unsigned)f2bf(v2) | ((unsigned)f2bf(v3) << 16);
                *((uint2*)&Ys[nrow][half * 32 + sub8 * 4]) = o;
                if (half == 0 && sub8 == 0) ds[nrow] = di;
            }
        }
    }
    __syncthreads();

    // MFMA phase: wave wid -> col tile [wid*16, wid*16+16)
    if (!wactive) return;
    bf16x8 af[2];
#pragma unroll
    for (int ks = 0; ks < 2; ++ks)
        af[ks] = *(const bf16x8*)&Ys[n16][ks * 32 + g16 * 8];
    f32x4 acc = {0.f, 0.f, 0.f, 0.f};
    acc = __builtin_amdgcn_mfma_f32_16x16x32_bf16(af[0], bf[0], acc, 0, 0, 0);
    acc = __builtin_amdgcn_mfma_f32_16x16x32_bf16(af[1], bf[1], acc, 0, 0, 0);
    const int col = wid * 16 + n16;
#pragma unroll
    for (int r = 0; r < 4; ++r) {
        const int row = base + g16 * 4 + r;
        if (row < M && col < NCO) {
            const unsigned short y = f2bf(acc[r] * ds[g16 * 4 + r]);
            if (NCO == 64) {
                unsigned short* plane = (wid < 2) ? Olo : Ohi;
                plane[(size_t)row * 32 + (wid & 1) * 16 + n16] = y;
            } else {
                Olo[(size_t)row * NCO + col] = y;
            }
        }
    }
}

// NC=40 aggregation + fused log_softmax. lane = grp(2b)*16 + sub(4b);
// lane owns cols [sub*4, sub*4+4); 4 edge rows per instruction.
__global__ void agg40_lsm_kernel(const unsigned short* __restrict__ G,
                                 const int* __restrict__ rowptr, const int* __restrict__ deg,
                                 const unsigned short* __restrict__ cidx,
                                 const float* __restrict__ dinv, const float* __restrict__ b,
                                 float* __restrict__ Y, int M) {
    constexpr int NC = 40;
    constexpr int NQ = 10;
    const int lane = threadIdx.x & 63;
    const int node = blockIdx.x * 4 + (threadIdx.x >> 6);
    if (node >= M) return;
    const int grp = lane >> 4;                 // 0..3
    const int sub = lane & 15;                 // 0..15
    const bool act = (sub < NQ);
    const int start = rowptr[node];
    const int cnt = deg[node];

    float a[4] = {0.f, 0.f, 0.f, 0.f};
    float c[4] = {0.f, 0.f, 0.f, 0.f};

    for (int base = 0; base < cnt; base += 64) {
        const int nthis = min(64, cnt - base);
        int myidx = (lane < nthis) ? (int)cidx[start + base + lane] : 0;
        int j = 0;
        for (; j + 8 <= nthis; j += 8) {
            int s0 = __shfl(myidx, j + grp, 64);
            int s1 = __shfl(myidx, j + 4 + grp, 64);
            if (act) {
                uint2 v0 = *(const uint2*)(G + (size_t)s0 * NC + sub * 4);
                uint2 v1 = *(const uint2*)(G + (size_t)s1 * NC + sub * 4);
                acc_bf16x4(v0, a);
                acc_bf16x4(v1, c);
            }
        }
        if (j + 4 <= nthis) {
            int s0 = __shfl(myidx, j + grp, 64);
            if (act) {
                uint2 v0 = *(const uint2*)(G + (size_t)s0 * NC + sub * 4);
                acc_bf16x4(v0, a);
            }
            j += 4;
        }
        const int rem = nthis - j;             // 0..3
        if (grp < rem) {
            int s0 = __shfl(myidx, j + grp, 64);
            if (act) {
                uint2 v0 = *(const uint2*)(G + (size_t)s0 * NC + sub * 4);
                acc_bf16x4(v0, c);
            }
        }
    }
#pragma unroll
    for (int k = 0; k < 4; ++k) a[k] += c[k];
#pragma unroll
    for (int k = 0; k < 4; ++k) {
        a[k] += __shfl_xor(a[k], 16, 64);
        a[k] += __shfl_xor(a[k], 32, 64);
    }
    float v[4];
    {
        float self[4] = {0.f, 0.f, 0.f, 0.f};
        float4 bb = make_float4(0.f, 0.f, 0.f, 0.f);
        if (act) {
            uint2 sv = *(const uint2*)(G + (size_t)node * NC + sub * 4);
            self[0] = bf2f((unsigned short)(sv.x & 0xffffu));
            self[1] = bf2f((unsigned short)(sv.x >> 16));
            self[2] = bf2f((unsigned short)(sv.y & 0xffffu));
            self[3] = bf2f((unsigned short)(sv.y >> 16));
            bb = *(const float4*)(b + sub * 4);
        }
        const float di = dinv[node];
        v[0] = fmaxf((a[0] + self[0]) * di + bb.x, 0.f);
        v[1] = fmaxf((a[1] + self[1]) * di + bb.y, 0.f);
        v[2] = fmaxf((a[2] + self[2]) * di + bb.z, 0.f);
        v[3] = fmaxf((a[3] + self[3]) * di + bb.w, 0.f);
    }
    float m = act ? fmaxf(fmaxf(v[0], v[1]), fmaxf(v[2], v[3])) : -INFINITY;
#pragma unroll
    for (int o = 1; o < 16; o <<= 1) m = fmaxf(m, __shfl_xor(m, o, 64));
    float es = act ? (expf(v[0] - m) + expf(v[1] - m) + expf(v[2] - m) + expf(v[3] - m)) : 0.f;
#pragma unroll
    for (int o = 1; o < 16; o <<= 1) es += __shfl_xor(es, o, 64);
    const float ls = logf(es);
    if (act && grp == 0) {
        *((float4*)(Y + (size_t)node * NC + sub * 4)) =
            make_float4(v[0] - m - ls, v[1] - m - ls, v[2] - m - ls, v[3] - m - ls);
    }
}

extern "C" void kernel_launch(void* const* d_in, const int* in_sizes, int n_in,
                              void* d_out, int out_size, void* d_ws, size_t ws_size,
                              hipStream_t stream) {
    const float* x  = (const float*)d_in[0];
    const int*   ei = (const int*)d_in[1];        // [2, E] int32
    const float* W1 = (const float*)d_in[2];
    const float* b1 = (const float*)d_in[3];
    const float* W2 = (const float*)d_in[4];
    const float* b2 = (const float*)d_in[5];
    const float* W3 = (const float*)d_in[6];
    const float* b3 = (const float*)d_in[7];
    float* out = (float*)d_out;

    const int M  = in_sizes[0] / DF;              // 50000
    const int E  = in_sizes[1] / 2;               // 800000
    (void)ws_size; (void)n_in; (void)out_size;

    const int* src = ei;
    const int* dst = ei + E;

    const size_t Ma = ((size_t)M + 63) & ~63ull;
    const size_t Ea = ((size_t)E + 63) & ~63ull;

    // workspace layout
    int* deg    = (int*)d_ws;                            // Ma
    int* rowptr = deg + Ma;                              // Ma
    int* cursor = rowptr + Ma;                           // Ma
    int* bsum   = cursor + Ma;                           // 256
    unsigned short* cidx = (unsigned short*)(bsum + 256);        // Ea (u16)
    float* dinv = (float*)(cidx + Ea);                   // Ma
    unsigned short* G0lo = (unsigned short*)(dinv + Ma);         // Ma*32
    unsigned short* G0hi = G0lo + Ma * 32;               // Ma*32
    unsigned short* G1lo = G0hi + Ma * 32;               // Ma*32
    unsigned short* G1hi = G1lo + Ma * 32;               // Ma*32
    unsigned short* G3   = G0lo;                         // Ma*40 (reuse G0 region)

    const int gN = (M + TB - 1) / TB;
    const int nb = gN;                   // scan blocks (196 <= 256)
    const int psize = (M + NPART - 1) / NPART;
    const int partGrd = NPART * 96;      // 8 partitions x 96 slices

    // --- CSR build + dinv (once, reused by all 3 layers) ---
    zero_int_kernel<<<gN, TB, 0, stream>>>(deg, M);
    count_deg_part_kernel<<<partGrd, TB, 0, stream>>>(dst, deg, E, psize);
    scan_block_kernel<<<nb, TB, 0, stream>>>(deg, rowptr, bsum, dinv, M);
    add_offsets_kernel<<<nb, TB, 0, stream>>>(rowptr, bsum, cursor, M, nb);
    fill_csr_part_kernel<<<partGrd, TB, 0, stream>>>(src, dst, cursor, cidx, E, psize);

    const int nt      = (M + 15) / 16;            // 16-row tiles
    const int gemmGrd = (nt + 3) / 4;             // 4 waves/block (layer-1 gemm)
    const int fusGrd  = nt;                       // 16 nodes/block (fused)
    const int aggGrd  = (M + 3) / 4;

    // layer-1 dense transform -> split planes
    gemm_mfma_kernel<<<gemmGrd, TB, 0, stream>>>(x, W1, dinv, G0lo, G0hi, M);
    // layer-1 aggregate (2-pass, L2-resident planes) + layer-2 GEMM
    aggmm_kernel<64><<<fusGrd, TB, 0, stream>>>(G0lo, G0hi, rowptr, deg, cidx,
                                                dinv, b1, W2, G1lo, G1hi, M);
    // layer-2 aggregate + layer-3 GEMM -> G3 (plain 40-wide)
    aggmm_kernel<40><<<fusGrd, TB, 0, stream>>>(G1lo, G1hi, rowptr, deg, cidx,
                                                dinv, b2, W3, G3, nullptr, M);
    // layer-3 aggregate + log_softmax
    agg40_lsm_kernel<<<aggGrd, TB, 0, stream>>>(G3, rowptr, deg, cidx, dinv, b3, out, M);
}

// Round 13
// 192.016 us; speedup vs baseline: 1.1934x; 1.1934x over previous
//
#include <hip/hip_runtime.h>
#include <math.h>

// ---------------------------------------------------------------------------
// GCN, atomic-free aggregation via per-call CSR (bucket by dst):
//   deg count (dst-partitioned) -> block scan(+dinv) -> add_offsets (fused
//   bsum scan) -> fill (dst-partitioned, XCD-local, u16)          [once]
//   gemm1 (MFMA 16x16x32 bf16, W frags in VGPRs, zero LDS): G1=(x@W1)*dinv
//   aggmm<64>: y1=relu(dinv*(G1self+gather)+b1) -> LDS[16][72] -> MFMA
//              G2=(Y1@W2)*dinv   [agg + next-layer GEMM fused per 16 nodes]
//   aggmm<40>: same with W3 -> G3
//   agg40_lsm: y3=relu(...b3); out=log_softmax(y3)
// aggmm blocks are 512 threads / 8 waves, 2 nodes per wave: r12 showed the
// gather is L3-latency-bound (FETCH 44MB on a 6.4MB set, VALUBusy 33%) —
// halving each wave's serial node chain + doubling resident waves raises MLP.
// (r12's 2-pass plane split REGRESSED: 2x traversal overhead, no L2 win.)
// Gather: lane=(grp<<3)|sub, uint4 (8 bf16), 8 edge rows/instr, butterfly
// shfl_xor(8|16|32). History: r7 4x4 reg-tile = occupancy crater; r9 LDS
// gemv = LDS-pipe bound; r10 MFMA-reg GEMM; r11 fusion (194.6us best).
// MFMA layouts (guide m89/m97): A lane(m=l&15,g=l>>4)=A[m][g*8+j];
//   B lane(n=l&15,g)=B[g*8+j][n]; C/D: col=l&15, row=(l>>4)*4+reg.
// cidx u16 (N_NODES=50000<65536).
// NOTE: no hipMemsetAsync — rocclr fillBuffer took 45.9us for 195KB in-graph.
// ---------------------------------------------------------------------------

#define DF 64
#define TB 256
#define NPART 8

typedef __attribute__((ext_vector_type(8))) short bf16x8;
typedef __attribute__((ext_vector_type(4))) float f32x4;

__device__ __forceinline__ unsigned short f2bf(float f) {
    union { float f; unsigned u; } c; c.f = f;
    unsigned u = c.u;
    return (unsigned short)((u + 0x7fffu + ((u >> 16) & 1u)) >> 16);   // RNE
}
__device__ __forceinline__ float bf2f(unsigned short h) {
    union { unsigned u; float f; } c; c.u = ((unsigned)h) << 16;
    return c.f;
}
__device__ __forceinline__ void acc_bf16x8(uint4 v, float* a) {
    a[0] += bf2f((unsigned short)(v.x & 0xffffu));
    a[1] += bf2f((unsigned short)(v.x >> 16));
    a[2] += bf2f((unsigned short)(v.y & 0xffffu));
    a[3] += bf2f((unsigned short)(v.y >> 16));
    a[4] += bf2f((unsigned short)(v.z & 0xffffu));
    a[5] += bf2f((unsigned short)(v.z >> 16));
    a[6] += bf2f((unsigned short)(v.w & 0xffffu));
    a[7] += bf2f((unsigned short)(v.w >> 16));
}
__device__ __forceinline__ void acc_bf16x4(uint2 v, float* a) {
    a[0] += bf2f((unsigned short)(v.x & 0xffffu));
    a[1] += bf2f((unsigned short)(v.x >> 16));
    a[2] += bf2f((unsigned short)(v.y & 0xffffu));
    a[3] += bf2f((unsigned short)(v.y >> 16));
}

__global__ void zero_int_kernel(int* __restrict__ p, int n) {
    int i = blockIdx.x * blockDim.x + threadIdx.x;
    if (i < n) p[i] = 0;
}

__global__ void count_deg_part_kernel(const int* __restrict__ dst, int* __restrict__ deg,
                                      int e, int psize) {
    const int p   = blockIdx.x & (NPART - 1);
    const int sl  = blockIdx.x / NPART;
    const int nsl = gridDim.x / NPART;
    const int lo = p * psize, hi = lo + psize;
    for (int i = sl * TB + threadIdx.x; i < e; i += nsl * TB) {
        int d = dst[i];
        if (d >= lo && d < hi) atomicAdd(&deg[d], 1);
    }
}

// per-block exclusive scan of deg -> ex (partial), block totals -> bsum; also dinv
__global__ void scan_block_kernel(const int* __restrict__ deg, int* __restrict__ ex,
                                  int* __restrict__ bsum, float* __restrict__ dinv, int n) {
    __shared__ int s[TB];
    const int t = threadIdx.x;
    const int i = blockIdx.x * TB + t;
    int v = (i < n) ? deg[i] : 0;
    if (i < n) dinv[i] = rsqrtf((float)(v + 1));   // +1 self-loop
    s[t] = v; __syncthreads();
#pragma unroll
    for (int o = 1; o < TB; o <<= 1) {
        int u = (t >= o) ? s[t - o] : 0;
        __syncthreads();
        s[t] += u;
        __syncthreads();
    }
    if (i < n) ex[i] = s[t] - v;
    if (t == TB - 1) bsum[blockIdx.x] = s[TB - 1];
}

// each block redundantly scans bsum (nb <= 256) in LDS, then offsets its slice
__global__ void add_offsets_kernel(int* __restrict__ ex, const int* __restrict__ bsum,
                                   int* __restrict__ cursor, int n, int nb) {
    __shared__ int s[TB];
    const int t = threadIdx.x;
    int v = (t < nb) ? bsum[t] : 0;
    s[t] = v; __syncthreads();
#pragma unroll
    for (int o = 1; o < TB; o <<= 1) {
        int u = (t >= o) ? s[t - o] : 0;
        __syncthreads();
        s[t] += u;
        __syncthreads();
    }
    const int boff = (blockIdx.x > 0) ? s[blockIdx.x - 1] : 0;
    const int i = blockIdx.x * TB + t;
    if (i < n) {
        int r = ex[i] + boff;
        ex[i] = r;
        cursor[i] = r;
    }
}

__global__ void fill_csr_part_kernel(const int* __restrict__ src, const int* __restrict__ dst,
                                     int* __restrict__ cursor,
                                     unsigned short* __restrict__ cidx, int e, int psize) {
    const int p   = blockIdx.x & (NPART - 1);
    const int sl  = blockIdx.x / NPART;
    const int nsl = gridDim.x / NPART;
    const int lo = p * psize, hi = lo + psize;
    for (int i = sl * TB + threadIdx.x; i < e; i += nsl * TB) {
        int d = dst[i];
        if (d >= lo && d < hi) {
            int pos = atomicAdd(&cursor[d], 1);
            cidx[pos] = (unsigned short)src[i];
        }
    }
}

// G[M x 64](bf16) = (X[M x 64] @ W1[64 x 64]) * dinv[row], via MFMA. Layer 1.
__global__ __launch_bounds__(256) void gemm_mfma_kernel(
        const float* __restrict__ X, const float* __restrict__ W,
        const float* __restrict__ dinv, unsigned short* __restrict__ G, int M) {
    const int lane = threadIdx.x & 63;
    const int wid  = threadIdx.x >> 6;         // 0..3
    const int t    = blockIdx.x * 4 + wid;     // row-tile index
    const int nt   = (M + 15) >> 4;
    if (t >= nt) return;
    const int n = lane & 15;
    const int g = lane >> 4;

    bf16x8 bf[4][2];
#pragma unroll
    for (int ct = 0; ct < 4; ++ct) {
        const int c = ct * 16 + n;
#pragma unroll
        for (int ks = 0; ks < 2; ++ks)
#pragma unroll
            for (int j = 0; j < 8; ++j)
                bf[ct][ks][j] = (short)f2bf(W[(ks * 32 + g * 8 + j) * 64 + c]);
    }

    const int row_a = t * 16 + n;
    const int ra = (row_a < M) ? row_a : (M - 1);
    bf16x8 af[2];
#pragma unroll
    for (int ks = 0; ks < 2; ++ks) {
        float4 p0 = *(const float4*)(X + (size_t)ra * 64 + ks * 32 + g * 8);
        float4 p1 = *(const float4*)(X + (size_t)ra * 64 + ks * 32 + g * 8 + 4);
        af[ks][0] = (short)f2bf(p0.x); af[ks][1] = (short)f2bf(p0.y);
        af[ks][2] = (short)f2bf(p0.z); af[ks][3] = (short)f2bf(p0.w);
        af[ks][4] = (short)f2bf(p1.x); af[ks][5] = (short)f2bf(p1.y);
        af[ks][6] = (short)f2bf(p1.z); af[ks][7] = (short)f2bf(p1.w);
    }

    const int rbase = t * 16 + g * 4;
    float di[4];
#pragma unroll
    for (int r = 0; r < 4; ++r) {
        int rr = rbase + r;
        di[r] = dinv[(rr < M) ? rr : (M - 1)];
    }

#pragma unroll
    for (int ct = 0; ct < 4; ++ct) {
        f32x4 acc = {0.f, 0.f, 0.f, 0.f};
        acc = __builtin_amdgcn_mfma_f32_16x16x32_bf16(af[0], bf[ct][0], acc, 0, 0, 0);
        acc = __builtin_amdgcn_mfma_f32_16x16x32_bf16(af[1], bf[ct][1], acc, 0, 0, 0);
        const int col = ct * 16 + n;
#pragma unroll
        for (int r = 0; r < 4; ++r) {
            const int row = rbase + r;
            if (row < M)
                G[(size_t)row * 64 + col] = f2bf(acc[r] * di[r]);
        }
    }
}

// Fused: aggregate 16 nodes (2 per wave, 8 waves) + next-layer MFMA GEMM.
// Gout[16 x NCO] = (relu(dinv*(self+gather)+b)[16 x 64] @ Wn[64 x NCO]) * dinv
template <int NCO>
__global__ __launch_bounds__(512) void aggmm_kernel(
        const unsigned short* __restrict__ G,
        const int* __restrict__ rowptr, const int* __restrict__ deg,
        const unsigned short* __restrict__ cidx,
        const float* __restrict__ dinv, const float* __restrict__ b,
        const float* __restrict__ Wn,
        unsigned short* __restrict__ Gout, int M) {
    __shared__ unsigned short Ys[16][72];      // +8 pad: stride 144B
    __shared__ float ds[16];
    const int tid  = threadIdx.x;
    const int lane = tid & 63;
    const int wid  = tid >> 6;                 // 0..7
    const int base = blockIdx.x * 16;
    const int grp = lane >> 3;                 // 0..7 edge slot
    const int sub = lane & 7;                  // 0..7 col octet
    const int n16 = lane & 15;
    const int g16 = lane >> 4;

    // B fragments for MFMA waves (col tile = wid), loaded before agg
    const bool wactive = (wid * 16 < NCO);     // wid<4 (64) or wid<3 (40)
    bf16x8 bf[2];
    if (wactive) {
        const int c = wid * 16 + n16;
#pragma unroll
        for (int ks = 0; ks < 2; ++ks)
#pragma unroll
            for (int j = 0; j < 8; ++j) {
                const int k = ks * 32 + g16 * 8 + j;
                float w = (c < NCO) ? Wn[k * NCO + c] : 0.f;
                bf[ks][j] = (short)f2bf(w);
            }
    }

    // agg phase: wave wid owns rows wid*2, wid*2+1 (2 serial nodes per wave)
    for (int i = 0; i < 2; ++i) {
        const int nrow  = wid * 2 + i;
        const int node0 = base + nrow;
        const int node  = (node0 < M) ? node0 : (M - 1);   // clamped: garbage ok
        const int start = rowptr[node];
        const int cnt   = deg[node];

        float a[8] = {0.f, 0.f, 0.f, 0.f, 0.f, 0.f, 0.f, 0.f};
        float c8[8] = {0.f, 0.f, 0.f, 0.f, 0.f, 0.f, 0.f, 0.f};
        for (int bs = 0; bs < cnt; bs += 64) {
            const int nthis = min(64, cnt - bs);
            int myidx = (lane < nthis) ? (int)cidx[start + bs + lane] : 0;
            int j = 0;
            for (; j + 16 <= nthis; j += 16) {
                int s0 = __shfl(myidx, j + grp, 64);
                int s1 = __shfl(myidx, j + 8 + grp, 64);
                uint4 v0 = *(const uint4*)(G + (size_t)s0 * 64 + sub * 8);
                uint4 v1 = *(const uint4*)(G + (size_t)s1 * 64 + sub * 8);
                acc_bf16x8(v0, a);
                acc_bf16x8(v1, c8);
            }
            if (j + 8 <= nthis) {
                int s0 = __shfl(myidx, j + grp, 64);
                uint4 v0 = *(const uint4*)(G + (size_t)s0 * 64 + sub * 8);
                acc_bf16x8(v0, a);
                j += 8;
            }
            const int rem = nthis - j;
            if (grp < rem) {
                int s0 = __shfl(myidx, j + grp, 64);
                uint4 v0 = *(const uint4*)(G + (size_t)s0 * 64 + sub * 8);
                acc_bf16x8(v0, c8);
            }
        }
#pragma unroll
        for (int k = 0; k < 8; ++k) a[k] += c8[k];
#pragma unroll
        for (int k = 0; k < 8; ++k) {
            a[k] += __shfl_xor(a[k], 8, 64);
            a[k] += __shfl_xor(a[k], 16, 64);
            a[k] += __shfl_xor(a[k], 32, 64);
        }
        if (grp == 0) {
            uint4 sv = *(const uint4*)(G + (size_t)node * 64 + sub * 8);
            float4 b0 = *(const float4*)(b + sub * 8);
            float4 b1 = *(const float4*)(b + sub * 8 + 4);
            const float di = dinv[node];
            float v[8];
            v[0] = fmaxf((a[0] + bf2f((unsigned short)(sv.x & 0xffffu))) * di + b0.x, 0.f);
            v[1] = fmaxf((a[1] + bf2f((unsigned short)(sv.x >> 16)))     * di + b0.y, 0.f);
            v[2] = fmaxf((a[2] + bf2f((unsigned short)(sv.y & 0xffffu))) * di + b0.z, 0.f);
            v[3] = fmaxf((a[3] + bf2f((unsigned short)(sv.y >> 16)))     * di + b0.w, 0.f);
            v[4] = fmaxf((a[4] + bf2f((unsigned short)(sv.z & 0xffffu))) * di + b1.x, 0.f);
            v[5] = fmaxf((a[5] + bf2f((unsigned short)(sv.z >> 16)))     * di + b1.y, 0.f);
            v[6] = fmaxf((a[6] + bf2f((unsigned short)(sv.w & 0xffffu))) * di + b1.z, 0.f);
            v[7] = fmaxf((a[7] + bf2f((unsigned short)(sv.w >> 16)))     * di + b1.w, 0.f);
            uint4 o;
            o.x = (unsigned)f2bf(v[0]) | ((unsigned)f2bf(v[1]) << 16);
            o.y = (unsigned)f2bf(v[2]) | ((unsigned)f2bf(v[3]) << 16);
            o.z = (unsigned)f2bf(v[4]) | ((unsigned)f2bf(v[5]) << 16);
            o.w = (unsigned)f2bf(v[6]) | ((unsigned)f2bf(v[7]) << 16);
            *((uint4*)&Ys[nrow][sub * 8]) = o;
            if (sub == 0) ds[nrow] = di;
        }
    }
    __syncthreads();

    // MFMA phase: wave wid (<NCO/16) -> col tile [wid*16, wid*16+16)
    if (!wactive) return;
    bf16x8 af[2];
#pragma unroll
    for (int ks = 0; ks < 2; ++ks)
        af[ks] = *(const bf16x8*)&Ys[n16][ks * 32 + g16 * 8];
    f32x4 acc = {0.f, 0.f, 0.f, 0.f};
    acc = __builtin_amdgcn_mfma_f32_16x16x32_bf16(af[0], bf[0], acc, 0, 0, 0);
    acc = __builtin_amdgcn_mfma_f32_16x16x32_bf16(af[1], bf[1], acc, 0, 0, 0);
    const int col = wid * 16 + n16;
#pragma unroll
    for (int r = 0; r < 4; ++r) {
        const int row = base + g16 * 4 + r;
        if (row < M && col < NCO)
            Gout[(size_t)row * NCO + col] = f2bf(acc[r] * ds[g16 * 4 + r]);
    }
}

// NC=40 aggregation + fused log_softmax. lane = grp(2b)*16 + sub(4b);
// lane owns cols [sub*4, sub*4+4); 4 edge rows per instruction.
__global__ void agg40_lsm_kernel(const unsigned short* __restrict__ G,
                                 const int* __restrict__ rowptr, const int* __restrict__ deg,
                                 const unsigned short* __restrict__ cidx,
                                 const float* __restrict__ dinv, const float* __restrict__ b,
                                 float* __restrict__ Y, int M) {
    constexpr int NC = 40;
    constexpr int NQ = 10;
    const int lane = threadIdx.x & 63;
    const int node = blockIdx.x * 4 + (threadIdx.x >> 6);
    if (node >= M) return;
    const int grp = lane >> 4;                 // 0..3
    const int sub = lane & 15;                 // 0..15
    const bool act = (sub < NQ);
    const int start = rowptr[node];
    const int cnt = deg[node];

    float a[4] = {0.f, 0.f, 0.f, 0.f};
    float c[4] = {0.f, 0.f, 0.f, 0.f};

    for (int base = 0; base < cnt; base += 64) {
        const int nthis = min(64, cnt - base);
        int myidx = (lane < nthis) ? (int)cidx[start + base + lane] : 0;
        int j = 0;
        for (; j + 8 <= nthis; j += 8) {
            int s0 = __shfl(myidx, j + grp, 64);
            int s1 = __shfl(myidx, j + 4 + grp, 64);
            if (act) {
                uint2 v0 = *(const uint2*)(G + (size_t)s0 * NC + sub * 4);
                uint2 v1 = *(const uint2*)(G + (size_t)s1 * NC + sub * 4);
                acc_bf16x4(v0, a);
                acc_bf16x4(v1, c);
            }
        }
        if (j + 4 <= nthis) {
            int s0 = __shfl(myidx, j + grp, 64);
            if (act) {
                uint2 v0 = *(const uint2*)(G + (size_t)s0 * NC + sub * 4);
                acc_bf16x4(v0, a);
            }
            j += 4;
        }
        const int rem = nthis - j;             // 0..3
        if (grp < rem) {
            int s0 = __shfl(myidx, j + grp, 64);
            if (act) {
                uint2 v0 = *(const uint2*)(G + (size_t)s0 * NC + sub * 4);
                acc_bf16x4(v0, c);
            }
        }
    }
#pragma unroll
    for (int k = 0; k < 4; ++k) a[k] += c[k];
#pragma unroll
    for (int k = 0; k < 4; ++k) {
        a[k] += __shfl_xor(a[k], 16, 64);
        a[k] += __shfl_xor(a[k], 32, 64);
    }
    float v[4];
    {
        float self[4] = {0.f, 0.f, 0.f, 0.f};
        float4 bb = make_float4(0.f, 0.f, 0.f, 0.f);
        if (act) {
            uint2 sv = *(const uint2*)(G + (size_t)node * NC + sub * 4);
            self[0] = bf2f((unsigned short)(sv.x & 0xffffu));
            self[1] = bf2f((unsigned short)(sv.x >> 16));
            self[2] = bf2f((unsigned short)(sv.y & 0xffffu));
            self[3] = bf2f((unsigned short)(sv.y >> 16));
            bb = *(const float4*)(b + sub * 4);
        }
        const float di = dinv[node];
        v[0] = fmaxf((a[0] + self[0]) * di + bb.x, 0.f);
        v[1] = fmaxf((a[1] + self[1]) * di + bb.y, 0.f);
        v[2] = fmaxf((a[2] + self[2]) * di + bb.z, 0.f);
        v[3] = fmaxf((a[3] + self[3]) * di + bb.w, 0.f);
    }
    float m = act ? fmaxf(fmaxf(v[0], v[1]), fmaxf(v[2], v[3])) : -INFINITY;
#pragma unroll
    for (int o = 1; o < 16; o <<= 1) m = fmaxf(m, __shfl_xor(m, o, 64));
    float es = act ? (expf(v[0] - m) + expf(v[1] - m) + expf(v[2] - m) + expf(v[3] - m)) : 0.f;
#pragma unroll
    for (int o = 1; o < 16; o <<= 1) es += __shfl_xor(es, o, 64);
    const float ls = logf(es);
    if (act && grp == 0) {
        *((float4*)(Y + (size_t)node * NC + sub * 4)) =
            make_float4(v[0] - m - ls, v[1] - m - ls, v[2] - m - ls, v[3] - m - ls);
    }
}

extern "C" void kernel_launch(void* const* d_in, const int* in_sizes, int n_in,
                              void* d_out, int out_size, void* d_ws, size_t ws_size,
                              hipStream_t stream) {
    const float* x  = (const float*)d_in[0];
    const int*   ei = (const int*)d_in[1];        // [2, E] int32
    const float* W1 = (const float*)d_in[2];
    const float* b1 = (const float*)d_in[3];
    const float* W2 = (const float*)d_in[4];
    const float* b2 = (const float*)d_in[5];
    const float* W3 = (const float*)d_in[6];
    const float* b3 = (const float*)d_in[7];
    float* out = (float*)d_out;

    const int M  = in_sizes[0] / DF;              // 50000
    const int E  = in_sizes[1] / 2;               // 800000
    (void)ws_size; (void)n_in; (void)out_size;

    const int* src = ei;
    const int* dst = ei + E;

    const size_t Ma = ((size_t)M + 63) & ~63ull;
    const size_t Ea = ((size_t)E + 63) & ~63ull;

    // workspace layout
    int* deg    = (int*)d_ws;                            // Ma
    int* rowptr = deg + Ma;                              // Ma
    int* cursor = rowptr + Ma;                           // Ma
    int* bsum   = cursor + Ma;                           // 256
    unsigned short* cidx = (unsigned short*)(bsum + 256);        // Ea (u16)
    float* dinv = (float*)(cidx + Ea);                   // Ma
    unsigned short* G0 = (unsigned short*)(dinv + Ma);           // Ma*64 (bf16)
    unsigned short* G1 = G0 + Ma * DF;                   // Ma*64 (bf16)

    const int gN = (M + TB - 1) / TB;
    const int nb = gN;                   // scan blocks (196 <= 256)
    const int psize = (M + NPART - 1) / NPART;
    const int partGrd = NPART * 96;      // 8 partitions x 96 slices

    // --- CSR build + dinv (once, reused by all 3 layers) ---
    zero_int_kernel<<<gN, TB, 0, stream>>>(deg, M);
    count_deg_part_kernel<<<partGrd, TB, 0, stream>>>(dst, deg, E, psize);
    scan_block_kernel<<<nb, TB, 0, stream>>>(deg, rowptr, bsum, dinv, M);
    add_offsets_kernel<<<nb, TB, 0, stream>>>(rowptr, bsum, cursor, M, nb);
    fill_csr_part_kernel<<<partGrd, TB, 0, stream>>>(src, dst, cursor, cidx, E, psize);

    const int nt      = (M + 15) / 16;            // 16-row tiles
    const int gemmGrd = (nt + 3) / 4;             // 4 waves/block (layer-1 gemm)
    const int fusGrd  = nt;                       // 16 nodes/block (fused)
    const int aggGrd  = (M + 3) / 4;

    // layer-1 dense transform
    gemm_mfma_kernel<<<gemmGrd, TB, 0, stream>>>(x, W1, dinv, G0, M);
    // layer-1 aggregate + layer-2 GEMM (fused; 512-thread blocks, 2 nodes/wave)
    aggmm_kernel<64><<<fusGrd, 512, 0, stream>>>(G0, rowptr, deg, cidx, dinv, b1, W2, G1, M);
    // layer-2 aggregate + layer-3 GEMM (fused)
    aggmm_kernel<40><<<fusGrd, 512, 0, stream>>>(G1, rowptr, deg, cidx, dinv, b2, W3, G0, M);
    // layer-3 aggregate + log_softmax
    agg40_lsm_kernel<<<aggGrd, TB, 0, stream>>>(G0, rowptr, deg, cidx, dinv, b3, out, M);
}

// Round 14
// 189.671 us; speedup vs baseline: 1.2082x; 1.0124x over previous
//
#include <hip/hip_runtime.h>
#include <math.h>

// ---------------------------------------------------------------------------
// GCN, atomic-free aggregation via per-call CSR (bucket by dst):
//   deg count (dst-partitioned) -> block scan(+dinv) -> add_offsets (fused
//   bsum scan) -> fill (dst-partitioned, XCD-local, u16)          [once]
//   gemm1 (MFMA 16x16x32 bf16, W frags in VGPRs, zero LDS): G1=(x@W1)*dinv
//   aggmm<64>: y1=relu(dinv*(G1self+gather)+b1) -> LDS[16][72] -> MFMA
//              G2=(Y1@W2)*dinv   [agg + next-layer GEMM fused per 16 nodes]
//   aggmm<40>: same with W3 -> G3
//   agg40_lsm: y3=relu(...b3); out=log_softmax(y3)
// aggmm: 512 thr / 8 waves, 2 nodes per wave, with the two nodes' gather
// chains INTERLEAVED (fast path deg<=64): both cidx chunks loaded up front,
// round-loop issues node0+node1 gathers adjacently -> 2x outstanding loads
// per wave. Diagnostic history: r11 fusion -25MB HBM = -2us (not HBM-bound);
// r12 plane split = regression (not L2-capacity-bound); r13 2x TLP = -1.3%
// (not wave-starved) -> residual lever is per-node chain ILP (this round).
// Gather: lane=(grp<<3)|sub, uint4 (8 bf16), 8 edge rows/instr, butterfly
// shfl_xor(8|16|32). r7: big reg tiles crater occupancy. r9: LDS gemv is
// LDS-pipe-bound. MFMA layouts (guide m89/m97).
// cidx u16 (N_NODES=50000<65536).
// NOTE: no hipMemsetAsync — rocclr fillBuffer took 45.9us for 195KB in-graph.
// ---------------------------------------------------------------------------

#define DF 64
#define TB 256
#define NPART 8

typedef __attribute__((ext_vector_type(8))) short bf16x8;
typedef __attribute__((ext_vector_type(4))) float f32x4;

__device__ __forceinline__ unsigned short f2bf(float f) {
    union { float f; unsigned u; } c; c.f = f;
    unsigned u = c.u;
    return (unsigned short)((u + 0x7fffu + ((u >> 16) & 1u)) >> 16);   // RNE
}
__device__ __forceinline__ float bf2f(unsigned short h) {
    union { unsigned u; float f; } c; c.u = ((unsigned)h) << 16;
    return c.f;
}
__device__ __forceinline__ void acc_bf16x8(uint4 v, float* a) {
    a[0] += bf2f((unsigned short)(v.x & 0xffffu));
    a[1] += bf2f((unsigned short)(v.x >> 16));
    a[2] += bf2f((unsigned short)(v.y & 0xffffu));
    a[3] += bf2f((unsigned short)(v.y >> 16));
    a[4] += bf2f((unsigned short)(v.z & 0xffffu));
    a[5] += bf2f((unsigned short)(v.z >> 16));
    a[6] += bf2f((unsigned short)(v.w & 0xffffu));
    a[7] += bf2f((unsigned short)(v.w >> 16));
}
__device__ __forceinline__ void acc_bf16x4(uint2 v, float* a) {
    a[0] += bf2f((unsigned short)(v.x & 0xffffu));
    a[1] += bf2f((unsigned short)(v.x >> 16));
    a[2] += bf2f((unsigned short)(v.y & 0xffffu));
    a[3] += bf2f((unsigned short)(v.y >> 16));
}

__global__ void zero_int_kernel(int* __restrict__ p, int n) {
    int i = blockIdx.x * blockDim.x + threadIdx.x;
    if (i < n) p[i] = 0;
}

__global__ void count_deg_part_kernel(const int* __restrict__ dst, int* __restrict__ deg,
                                      int e, int psize) {
    const int p   = blockIdx.x & (NPART - 1);
    const int sl  = blockIdx.x / NPART;
    const int nsl = gridDim.x / NPART;
    const int lo = p * psize, hi = lo + psize;
    for (int i = sl * TB + threadIdx.x; i < e; i += nsl * TB) {
        int d = dst[i];
        if (d >= lo && d < hi) atomicAdd(&deg[d], 1);
    }
}

// per-block exclusive scan of deg -> ex (partial), block totals -> bsum; also dinv
__global__ void scan_block_kernel(const int* __restrict__ deg, int* __restrict__ ex,
                                  int* __restrict__ bsum, float* __restrict__ dinv, int n) {
    __shared__ int s[TB];
    const int t = threadIdx.x;
    const int i = blockIdx.x * TB + t;
    int v = (i < n) ? deg[i] : 0;
    if (i < n) dinv[i] = rsqrtf((float)(v + 1));   // +1 self-loop
    s[t] = v; __syncthreads();
#pragma unroll
    for (int o = 1; o < TB; o <<= 1) {
        int u = (t >= o) ? s[t - o] : 0;
        __syncthreads();
        s[t] += u;
        __syncthreads();
    }
    if (i < n) ex[i] = s[t] - v;
    if (t == TB - 1) bsum[blockIdx.x] = s[TB - 1];
}

// each block redundantly scans bsum (nb <= 256) in LDS, then offsets its slice
__global__ void add_offsets_kernel(int* __restrict__ ex, const int* __restrict__ bsum,
                                   int* __restrict__ cursor, int n, int nb) {
    __shared__ int s[TB];
    const int t = threadIdx.x;
    int v = (t < nb) ? bsum[t] : 0;
    s[t] = v; __syncthreads();
#pragma unroll
    for (int o = 1; o < TB; o <<= 1) {
        int u = (t >= o) ? s[t - o] : 0;
        __syncthreads();
        s[t] += u;
        __syncthreads();
    }
    const int boff = (blockIdx.x > 0) ? s[blockIdx.x - 1] : 0;
    const int i = blockIdx.x * TB + t;
    if (i < n) {
        int r = ex[i] + boff;
        ex[i] = r;
        cursor[i] = r;
    }
}

__global__ void fill_csr_part_kernel(const int* __restrict__ src, const int* __restrict__ dst,
                                     int* __restrict__ cursor,
                                     unsigned short* __restrict__ cidx, int e, int psize) {
    const int p   = blockIdx.x & (NPART - 1);
    const int sl  = blockIdx.x / NPART;
    const int nsl = gridDim.x / NPART;
    const int lo = p * psize, hi = lo + psize;
    for (int i = sl * TB + threadIdx.x; i < e; i += nsl * TB) {
        int d = dst[i];
        if (d >= lo && d < hi) {
            int pos = atomicAdd(&cursor[d], 1);
            cidx[pos] = (unsigned short)src[i];
        }
    }
}

// G[M x 64](bf16) = (X[M x 64] @ W1[64 x 64]) * dinv[row], via MFMA. Layer 1.
__global__ __launch_bounds__(256) void gemm_mfma_kernel(
        const float* __restrict__ X, const float* __restrict__ W,
        const float* __restrict__ dinv, unsigned short* __restrict__ G, int M) {
    const int lane = threadIdx.x & 63;
    const int wid  = threadIdx.x >> 6;         // 0..3
    const int t    = blockIdx.x * 4 + wid;     // row-tile index
    const int nt   = (M + 15) >> 4;
    if (t >= nt) return;
    const int n = lane & 15;
    const int g = lane >> 4;

    bf16x8 bf[4][2];
#pragma unroll
    for (int ct = 0; ct < 4; ++ct) {
        const int c = ct * 16 + n;
#pragma unroll
        for (int ks = 0; ks < 2; ++ks)
#pragma unroll
            for (int j = 0; j < 8; ++j)
                bf[ct][ks][j] = (short)f2bf(W[(ks * 32 + g * 8 + j) * 64 + c]);
    }

    const int row_a = t * 16 + n;
    const int ra = (row_a < M) ? row_a : (M - 1);
    bf16x8 af[2];
#pragma unroll
    for (int ks = 0; ks < 2; ++ks) {
        float4 p0 = *(const float4*)(X + (size_t)ra * 64 + ks * 32 + g * 8);
        float4 p1 = *(const float4*)(X + (size_t)ra * 64 + ks * 32 + g * 8 + 4);
        af[ks][0] = (short)f2bf(p0.x); af[ks][1] = (short)f2bf(p0.y);
        af[ks][2] = (short)f2bf(p0.z); af[ks][3] = (short)f2bf(p0.w);
        af[ks][4] = (short)f2bf(p1.x); af[ks][5] = (short)f2bf(p1.y);
        af[ks][6] = (short)f2bf(p1.z); af[ks][7] = (short)f2bf(p1.w);
    }

    const int rbase = t * 16 + g * 4;
    float di[4];
#pragma unroll
    for (int r = 0; r < 4; ++r) {
        int rr = rbase + r;
        di[r] = dinv[(rr < M) ? rr : (M - 1)];
    }

#pragma unroll
    for (int ct = 0; ct < 4; ++ct) {
        f32x4 acc = {0.f, 0.f, 0.f, 0.f};
        acc = __builtin_amdgcn_mfma_f32_16x16x32_bf16(af[0], bf[ct][0], acc, 0, 0, 0);
        acc = __builtin_amdgcn_mfma_f32_16x16x32_bf16(af[1], bf[ct][1], acc, 0, 0, 0);
        const int col = ct * 16 + n;
#pragma unroll
        for (int r = 0; r < 4; ++r) {
            const int row = rbase + r;
            if (row < M)
                G[(size_t)row * 64 + col] = f2bf(acc[r] * di[r]);
        }
    }
}

// Fused: aggregate 16 nodes (2 per wave, 8 waves, chains interleaved) +
// next-layer MFMA GEMM.
template <int NCO>
__global__ __launch_bounds__(512) void aggmm_kernel(
        const unsigned short* __restrict__ G,
        const int* __restrict__ rowptr, const int* __restrict__ deg,
        const unsigned short* __restrict__ cidx,
        const float* __restrict__ dinv, const float* __restrict__ b,
        const float* __restrict__ Wn,
        unsigned short* __restrict__ Gout, int M) {
    __shared__ unsigned short Ys[16][72];      // +8 pad: stride 144B
    __shared__ float ds[16];
    const int tid  = threadIdx.x;
    const int lane = tid & 63;
    const int wid  = tid >> 6;                 // 0..7
    const int base = blockIdx.x * 16;
    const int grp = lane >> 3;                 // 0..7 edge slot
    const int sub = lane & 7;                  // 0..7 col octet
    const int n16 = lane & 15;
    const int g16 = lane >> 4;

    // B fragments for MFMA waves (col tile = wid), loaded before agg
    const bool wactive = (wid * 16 < NCO);     // wid<4 (64) or wid<3 (40)
    bf16x8 bf[2];
    if (wactive) {
        const int c = wid * 16 + n16;
#pragma unroll
        for (int ks = 0; ks < 2; ++ks)
#pragma unroll
            for (int j = 0; j < 8; ++j) {
                const int k = ks * 32 + g16 * 8 + j;
                float w = (c < NCO) ? Wn[k * NCO + c] : 0.f;
                bf[ks][j] = (short)f2bf(w);
            }
    }

    // agg phase: wave wid owns rows wid*2, wid*2+1; chains interleaved
    const int nrow0 = wid * 2;
    const int node0 = min(base + nrow0, M - 1);        // clamped: garbage ok
    const int node1 = min(base + nrow0 + 1, M - 1);
    const int start0 = rowptr[node0], cnt0 = deg[node0];
    const int start1 = rowptr[node1], cnt1 = deg[node1];

    float a0[8] = {0.f, 0.f, 0.f, 0.f, 0.f, 0.f, 0.f, 0.f};
    float a1[8] = {0.f, 0.f, 0.f, 0.f, 0.f, 0.f, 0.f, 0.f};

    if (cnt0 <= 64 && cnt1 <= 64) {
        // fast path: both cidx chunks up front, rounds issue both gathers
        int idx0 = (lane < cnt0) ? (int)cidx[start0 + lane] : 0;
        int idx1 = (lane < cnt1) ? (int)cidx[start1 + lane] : 0;
        const int cmax = max(cnt0, cnt1);
        for (int e = grp; ; e += 8) {
            const bool p0 = e < cnt0, p1 = e < cnt1;
            if (e >= cmax) break;
            int s0 = __shfl(idx0, e, 64);
            int s1 = __shfl(idx1, e, 64);
            if (p0) {
                uint4 v = *(const uint4*)(G + (size_t)s0 * 64 + sub * 8);
                acc_bf16x8(v, a0);
            }
            if (p1) {
                uint4 v = *(const uint4*)(G + (size_t)s1 * 64 + sub * 8);
                acc_bf16x8(v, a1);
            }
        }
    } else {
        // slow path (deg>64, rare): sequential chunked per node
        for (int which = 0; which < 2; ++which) {
            float* a = which ? a1 : a0;
            const int start = which ? start1 : start0;
            const int cnt   = which ? cnt1 : cnt0;
            for (int bs = 0; bs < cnt; bs += 64) {
                const int nthis = min(64, cnt - bs);
                int myidx = (lane < nthis) ? (int)cidx[start + bs + lane] : 0;
                for (int j = grp; j < nthis; j += 8) {
                    int s = __shfl(myidx, j, 64);
                    uint4 v = *(const uint4*)(G + (size_t)s * 64 + sub * 8);
                    acc_bf16x8(v, a);
                }
            }
        }
    }
    // butterflies (both nodes interleaved for ILP)
#pragma unroll
    for (int k = 0; k < 8; ++k) {
        a0[k] += __shfl_xor(a0[k], 8, 64);
        a1[k] += __shfl_xor(a1[k], 8, 64);
        a0[k] += __shfl_xor(a0[k], 16, 64);
        a1[k] += __shfl_xor(a1[k], 16, 64);
        a0[k] += __shfl_xor(a0[k], 32, 64);
        a1[k] += __shfl_xor(a1[k], 32, 64);
    }
    if (grp == 0) {
#pragma unroll
        for (int i = 0; i < 2; ++i) {
            const float* a = i ? a1 : a0;
            const int node = i ? node1 : node0;
            uint4 sv = *(const uint4*)(G + (size_t)node * 64 + sub * 8);
            float4 b0 = *(const float4*)(b + sub * 8);
            float4 b1 = *(const float4*)(b + sub * 8 + 4);
            const float di = dinv[node];
            float v[8];
            v[0] = fmaxf((a[0] + bf2f((unsigned short)(sv.x & 0xffffu))) * di + b0.x, 0.f);
            v[1] = fmaxf((a[1] + bf2f((unsigned short)(sv.x >> 16)))     * di + b0.y, 0.f);
            v[2] = fmaxf((a[2] + bf2f((unsigned short)(sv.y & 0xffffu))) * di + b0.z, 0.f);
            v[3] = fmaxf((a[3] + bf2f((unsigned short)(sv.y >> 16)))     * di + b0.w, 0.f);
            v[4] = fmaxf((a[4] + bf2f((unsigned short)(sv.z & 0xffffu))) * di + b1.x, 0.f);
            v[5] = fmaxf((a[5] + bf2f((unsigned short)(sv.z >> 16)))     * di + b1.y, 0.f);
            v[6] = fmaxf((a[6] + bf2f((unsigned short)(sv.w & 0xffffu))) * di + b1.z, 0.f);
            v[7] = fmaxf((a[7] + bf2f((unsigned short)(sv.w >> 16)))     * di + b1.w, 0.f);
            uint4 o;
            o.x = (unsigned)f2bf(v[0]) | ((unsigned)f2bf(v[1]) << 16);
            o.y = (unsigned)f2bf(v[2]) | ((unsigned)f2bf(v[3]) << 16);
            o.z = (unsigned)f2bf(v[4]) | ((unsigned)f2bf(v[5]) << 16);
            o.w = (unsigned)f2bf(v[6]) | ((unsigned)f2bf(v[7]) << 16);
            *((uint4*)&Ys[nrow0 + i][sub * 8]) = o;
            if (sub == 0) ds[nrow0 + i] = di;
        }
    }
    __syncthreads();

    // MFMA phase: wave wid (<NCO/16) -> col tile [wid*16, wid*16+16)
    if (!wactive) return;
    bf16x8 af[2];
#pragma unroll
    for (int ks = 0; ks < 2; ++ks)
        af[ks] = *(const bf16x8*)&Ys[n16][ks * 32 + g16 * 8];
    f32x4 acc = {0.f, 0.f, 0.f, 0.f};
    acc = __builtin_amdgcn_mfma_f32_16x16x32_bf16(af[0], bf[0], acc, 0, 0, 0);
    acc = __builtin_amdgcn_mfma_f32_16x16x32_bf16(af[1], bf[1], acc, 0, 0, 0);
    const int col = wid * 16 + n16;
#pragma unroll
    for (int r = 0; r < 4; ++r) {
        const int row = base + g16 * 4 + r;
        if (row < M && col < NCO)
            Gout[(size_t)row * NCO + col] = f2bf(acc[r] * ds[g16 * 4 + r]);
    }
}

// NC=40 aggregation + fused log_softmax. lane = grp(2b)*16 + sub(4b);
// lane owns cols [sub*4, sub*4+4); 4 edge rows per instruction.
__global__ void agg40_lsm_kernel(const unsigned short* __restrict__ G,
                                 const int* __restrict__ rowptr, const int* __restrict__ deg,
                                 const unsigned short* __restrict__ cidx,
                                 const float* __restrict__ dinv, const float* __restrict__ b,
                                 float* __restrict__ Y, int M) {
    constexpr int NC = 40;
    constexpr int NQ = 10;
    const int lane = threadIdx.x & 63;
    const int node = blockIdx.x * 4 + (threadIdx.x >> 6);
    if (node >= M) return;
    const int grp = lane >> 4;                 // 0..3
    const int sub = lane & 15;                 // 0..15
    const bool act = (sub < NQ);
    const int start = rowptr[node];
    const int cnt = deg[node];

    float a[4] = {0.f, 0.f, 0.f, 0.f};
    float c[4] = {0.f, 0.f, 0.f, 0.f};

    for (int base = 0; base < cnt; base += 64) {
        const int nthis = min(64, cnt - base);
        int myidx = (lane < nthis) ? (int)cidx[start + base + lane] : 0;
        int j = 0;
        for (; j + 8 <= nthis; j += 8) {
            int s0 = __shfl(myidx, j + grp, 64);
            int s1 = __shfl(myidx, j + 4 + grp, 64);
            if (act) {
                uint2 v0 = *(const uint2*)(G + (size_t)s0 * NC + sub * 4);
                uint2 v1 = *(const uint2*)(G + (size_t)s1 * NC + sub * 4);
                acc_bf16x4(v0, a);
                acc_bf16x4(v1, c);
            }
        }
        if (j + 4 <= nthis) {
            int s0 = __shfl(myidx, j + grp, 64);
            if (act) {
                uint2 v0 = *(const uint2*)(G + (size_t)s0 * NC + sub * 4);
                acc_bf16x4(v0, a);
            }
            j += 4;
        }
        const int rem = nthis - j;             // 0..3
        if (grp < rem) {
            int s0 = __shfl(myidx, j + grp, 64);
            if (act) {
                uint2 v0 = *(const uint2*)(G + (size_t)s0 * NC + sub * 4);
                acc_bf16x4(v0, c);
            }
        }
    }
#pragma unroll
    for (int k = 0; k < 4; ++k) a[k] += c[k];
#pragma unroll
    for (int k = 0; k < 4; ++k) {
        a[k] += __shfl_xor(a[k], 16, 64);
        a[k] += __shfl_xor(a[k], 32, 64);
    }
    float v[4];
    {
        float self[4] = {0.f, 0.f, 0.f, 0.f};
        float4 bb = make_float4(0.f, 0.f, 0.f, 0.f);
        if (act) {
            uint2 sv = *(const uint2*)(G + (size_t)node * NC + sub * 4);
            self[0] = bf2f((unsigned short)(sv.x & 0xffffu));
            self[1] = bf2f((unsigned short)(sv.x >> 16));
            self[2] = bf2f((unsigned short)(sv.y & 0xffffu));
            self[3] = bf2f((unsigned short)(sv.y >> 16));
            bb = *(const float4*)(b + sub * 4);
        }
        const float di = dinv[node];
        v[0] = fmaxf((a[0] + self[0]) * di + bb.x, 0.f);
        v[1] = fmaxf((a[1] + self[1]) * di + bb.y, 0.f);
        v[2] = fmaxf((a[2] + self[2]) * di + bb.z, 0.f);
        v[3] = fmaxf((a[3] + self[3]) * di + bb.w, 0.f);
    }
    float m = act ? fmaxf(fmaxf(v[0], v[1]), fmaxf(v[2], v[3])) : -INFINITY;
#pragma unroll
    for (int o = 1; o < 16; o <<= 1) m = fmaxf(m, __shfl_xor(m, o, 64));
    float es = act ? (expf(v[0] - m) + expf(v[1] - m) + expf(v[2] - m) + expf(v[3] - m)) : 0.f;
#pragma unroll
    for (int o = 1; o < 16; o <<= 1) es += __shfl_xor(es, o, 64);
    const float ls = logf(es);
    if (act && grp == 0) {
        *((float4*)(Y + (size_t)node * NC + sub * 4)) =
            make_float4(v[0] - m - ls, v[1] - m - ls, v[2] - m - ls, v[3] - m - ls);
    }
}

extern "C" void kernel_launch(void* const* d_in, const int* in_sizes, int n_in,
                              void* d_out, int out_size, void* d_ws, size_t ws_size,
                              hipStream_t stream) {
    const float* x  = (const float*)d_in[0];
    const int*   ei = (const int*)d_in[1];        // [2, E] int32
    const float* W1 = (const float*)d_in[2];
    const float* b1 = (const float*)d_in[3];
    const float* W2 = (const float*)d_in[4];
    const float* b2 = (const float*)d_in[5];
    const float* W3 = (const float*)d_in[6];
    const float* b3 = (const float*)d_in[7];
    float* out = (float*)d_out;

    const int M  = in_sizes[0] / DF;              // 50000
    const int E  = in_sizes[1] / 2;               // 800000
    (void)ws_size; (void)n_in; (void)out_size;

    const int* src = ei;
    const int* dst = ei + E;

    const size_t Ma = ((size_t)M + 63) & ~63ull;
    const size_t Ea = ((size_t)E + 63) & ~63ull;

    // workspace layout
    int* deg    = (int*)d_ws;                            // Ma
    int* rowptr = deg + Ma;                              // Ma
    int* cursor = rowptr + Ma;                           // Ma
    int* bsum   = cursor + Ma;                           // 256
    unsigned short* cidx = (unsigned short*)(bsum + 256);        // Ea (u16)
    float* dinv = (float*)(cidx + Ea);                   // Ma
    unsigned short* G0 = (unsigned short*)(dinv + Ma);           // Ma*64 (bf16)
    unsigned short* G1 = G0 + Ma * DF;                   // Ma*64 (bf16)

    const int gN = (M + TB - 1) / TB;
    const int nb = gN;                   // scan blocks (196 <= 256)
    const int psize = (M + NPART - 1) / NPART;
    const int partGrd = NPART * 96;      // 8 partitions x 96 slices

    // --- CSR build + dinv (once, reused by all 3 layers) ---
    zero_int_kernel<<<gN, TB, 0, stream>>>(deg, M);
    count_deg_part_kernel<<<partGrd, TB, 0, stream>>>(dst, deg, E, psize);
    scan_block_kernel<<<nb, TB, 0, stream>>>(deg, rowptr, bsum, dinv, M);
    add_offsets_kernel<<<nb, TB, 0, stream>>>(rowptr, bsum, cursor, M, nb);
    fill_csr_part_kernel<<<partGrd, TB, 0, stream>>>(src, dst, cursor, cidx, E, psize);

    const int nt      = (M + 15) / 16;            // 16-row tiles
    const int gemmGrd = (nt + 3) / 4;             // 4 waves/block (layer-1 gemm)
    const int fusGrd  = nt;                       // 16 nodes/block (fused)
    const int aggGrd  = (M + 3) / 4;

    // layer-1 dense transform
    gemm_mfma_kernel<<<gemmGrd, TB, 0, stream>>>(x, W1, dinv, G0, M);
    // layer-1 aggregate + layer-2 GEMM (fused; interleaved 2-node chains)
    aggmm_kernel<64><<<fusGrd, 512, 0, stream>>>(G0, rowptr, deg, cidx, dinv, b1, W2, G1, M);
    // layer-2 aggregate + layer-3 GEMM (fused)
    aggmm_kernel<40><<<fusGrd, 512, 0, stream>>>(G1, rowptr, deg, cidx, dinv, b2, W3, G0, M);
    // layer-3 aggregate + log_softmax
    agg40_lsm_kernel<<<aggGrd, TB, 0, stream>>>(G0, rowptr, deg, cidx, dinv, b3, out, M);
}